// Round 11
// baseline (4008.894 us; speedup 1.0000x reference)
//
#include <hip/hip_runtime.h>

// Two-layer tanh RNN, H=32, B=64, T=16384. Latency-bound sequential scan.
//
// Round-11: R10's 2-wave producer/consumer split, with the per-step LDS
// h-broadcast (ds_write + 8 ds_read_b128: TWO serialized DS passes) replaced
// by 32 uniform-address ds_bpermute (ONE DS pass, register->register).
// Wave A (h0 chain): lower lanes own Whh0 rows; upper lanes own Wih1 rows and
// publish u(t-1)=b1+Wih1.h0n(t-1) to a double-buffered LDS window ring
// (off-critical-cycle). Wave B (h1 chain, one window behind): lower lanes own
// Whh1 rows (consume u), upper lanes own Wout (out(t-1) free from the same
// broadcast). B's loop has NO LDS writes -> u-reads hoistable/off-cycle.
// Barrier per 32-step window; R10's proven indexing/epilogues retained.

#define T_LEN 16384
#define B_SZ  64
#define NW    (T_LEN / 32)   // 512 windows

__device__ __forceinline__ float rl(float v, int lane) {
  return __int_as_float(__builtin_amdgcn_readlane(__float_as_int(v), lane));
}

__device__ __forceinline__ float bp(int addr, float v) {
  return __int_as_float(__builtin_amdgcn_ds_bpermute(addr, __float_as_int(v)));
}

__device__ __forceinline__ float tanh_fast(float v) {
  // tanh(x) = 1 - 2/(exp(2x)+1); saturates correctly at +/-inf.
  float e = __expf(2.0f * v);
  return 1.0f - __fdividef(2.0f, e + 1.0f);
}

__global__ __launch_bounds__(128, 1) void rnn2_kernel(
    const float* __restrict__ x,    const float* __restrict__ hs,
    const float* __restrict__ Wih0, const float* __restrict__ Whh0,
    const float* __restrict__ bih0, const float* __restrict__ bhh0,
    const float* __restrict__ Wih1, const float* __restrict__ Whh1,
    const float* __restrict__ bih1, const float* __restrict__ bhh1,
    const float* __restrict__ Wout, const float* __restrict__ bout,
    float* __restrict__ out)
{
  __shared__ __align__(16) float uwin[2][2048];  // A->B; slot t2: [t2*64+32+r]=u[r]

  const int  tid = (int)threadIdx.x;
  const int  wv  = tid >> 6;           // 0 = wave A (h0), 1 = wave B (h1)
  const int  m   = tid & 63;
  const int  r   = m & 31;
  const bool up  = (m >= 32);
  const int  b   = (int)blockIdx.x;

  // One 32-float weight row per lane:
  //  A: lower = Whh0 row r, upper = Wih1 row r.  B: lower = Whh1 row r, upper = Wout.
  const float* wrow;
  if (wv == 0) wrow = up ? (Wih1 + r * 32) : (Whh0 + r * 32);
  else         wrow = up ? Wout            : (Whh1 + r * 32);
  float w[32];
#pragma unroll
  for (int k = 0; k < 8; ++k) {
    float4 q = ((const float4*)wrow)[k];
    w[4*k] = q.x; w[4*k+1] = q.y; w[4*k+2] = q.z; w[4*k+3] = q.w;
  }

  // Broadcast addresses pinned in VGPRs (keeps v_movs out of the hot loop).
  int adr[32];
#pragma unroll
  for (int j = 0; j < 32; ++j) {
    adr[j] = j * 4;
    asm volatile("" : "+v"(adr[j]));
  }

  float xw = 0.f, bini = 0.f;
  if (wv == 0) {
    if (!up) { xw = Wih0[r]; bini = bih0[r] + bhh0[r]; }  // layer-0 bias
    else     { bini = bih1[r] + bhh1[r]; }                // b1 folded into u
  }
  const float bo = bout[0];

  // Recurrent state in registers; lanes 0..31 meaningful (bpermute reads
  // only addresses 0..124 = lanes 0..31; upper lanes' copies are junk-safe).
  float h0 = hs[b * 32 + r];           // wave A
  float h1 = hs[2048 + b * 32 + r];    // wave B

  const float* xb   = x + (size_t)b * T_LEN;
  float*       outp = out + (size_t)b * T_LEN;       // outs[b*T + t]
  float*       hf   = out + (size_t)B_SZ * T_LEN;    // h_final [2,B,H]

  float obuf = 0.f;
  float xchunk = xb[r];                // lanes hold x(0..31) (A only uses)

  for (int wdx = 0; wdx <= NW; ++wdx) {
    if (wv == 0) {
      if (wdx < NW) {
        const int tb = 32 * wdx;
        int nid = tb + 32 + r; if (nid > T_LEN - 1) nid = T_LEN - 1;
        float xnext = xb[nid];         // prefetch next window
        float* ub = &uwin[wdx & 1][0];
#pragma unroll 4
        for (int t2 = 0; t2 < 32; ++t2) {
          // Single-pass broadcast of h0n(tb+t2-1) + row dot.
          float a0 = bini, a1 = 0.f, a2 = 0.f, a3 = 0.f;
#pragma unroll
          for (int j = 0; j < 32; j += 4) {
            a0 = fmaf(w[j],   bp(adr[j],   h0), a0);
            a1 = fmaf(w[j+1], bp(adr[j+1], h0), a1);
            a2 = fmaf(w[j+2], bp(adr[j+2], h0), a2);
            a3 = fmaf(w[j+3], bp(adr[j+3], h0), a3);
          }
          float acc = (a0 + a1) + (a2 + a3);  // lower: b0+Whh0.h0; upper: u(t-1)[r]
          ub[t2 * 64 + m] = acc;              // all-lane publish (upper half used)
          float xv = rl(xchunk, t2);
          h0 = tanh_fast(fmaf(xv, xw, acc));  // lower: h0n(tb+t2); upper: junk
        }
        xchunk = xnext;
      }
    } else {
      if (wdx >= 1) {
        const int wb = wdx - 1;               // steps t = 32*wb-1 .. 32*wb+30
        const float* ub = &uwin[wb & 1][0];
#pragma unroll 4
        for (int t2 = 0; t2 < 32; ++t2) {
          const int t = 32 * wb - 1 + t2;
          float uval = ub[t2 * 64 + 32 + r];  // u(t)[r]; off-cycle (no LDS writes)
          float a0 = up ? 0.f : uval, a1 = 0.f, a2 = 0.f, a3 = 0.f;
#pragma unroll
          for (int j = 0; j < 32; j += 4) {
            a0 = fmaf(w[j],   bp(adr[j],   h1), a0);
            a1 = fmaf(w[j+1], bp(adr[j+1], h1), a1);
            a2 = fmaf(w[j+2], bp(adr[j+2], h1), a2);
            a3 = fmaf(w[j+3], bp(adr[j+3], h1), a3);
          }
          float acc = (a0 + a1) + (a2 + a3);  // lower: pre-h1(t); upper: out(t-1)-bo
          float h1n = tanh_fast(acc);
          obuf = (m == 32 + t2) ? acc : obuf; // upper lane t2 keeps out(t-1)
          h1 = (t >= 0) ? h1n : h1;           // uniform guard (skips wb=0,t2=0)
        }
        const int idx = 32 * wb - 2 + r;      // upper lane r holds out(idx)
        if (up && idx >= 0) outp[idx] = obuf + bo;   // coalesced 32-store
      }
    }
    __syncthreads();   // window handoff (uwin parity swap)
  }

  // Epilogue 1 (wave A): publish u(T-1) from h0n(T-1) into uwin[0].
  if (wv == 0) {
    float a0 = bini, a1 = 0.f, a2 = 0.f, a3 = 0.f;
#pragma unroll
    for (int j = 0; j < 32; j += 4) {
      a0 = fmaf(w[j],   bp(adr[j],   h0), a0);
      a1 = fmaf(w[j+1], bp(adr[j+1], h0), a1);
      a2 = fmaf(w[j+2], bp(adr[j+2], h0), a2);
      a3 = fmaf(w[j+3], bp(adr[j+3], h0), a3);
    }
    uwin[0][m] = (a0 + a1) + (a2 + a3);       // [32+r] = u(T-1)[r]
    if (!up) hf[b * 32 + r] = h0;             // h_final layer 0 = h0n(T-1)
  }
  __syncthreads();

  // Epilogue 2 (wave B): h1n(T-1), out(T-2), out(T-1).
  if (wv == 1) {
    float uT = uwin[0][32 + r];
    float a0 = up ? 0.f : uT, a1 = 0.f, a2 = 0.f, a3 = 0.f;
#pragma unroll
    for (int j = 0; j < 32; j += 4) {
      a0 = fmaf(w[j],   bp(adr[j],   h1), a0);   // h1n(T-2) broadcast
      a1 = fmaf(w[j+1], bp(adr[j+1], h1), a1);
      a2 = fmaf(w[j+2], bp(adr[j+2], h1), a2);
      a3 = fmaf(w[j+3], bp(adr[j+3], h1), a3);
    }
    float acc = (a0 + a1) + (a2 + a3);
    if (m == 32) outp[T_LEN - 2] = acc + bo;  // out(T-2) = Wout.h1n(T-2)+bo
    float h1T = tanh_fast(acc);               // lower: h1n(T-1)
    float c0 = 0.f, c1 = 0.f, c2 = 0.f, c3 = 0.f;
#pragma unroll
    for (int j = 0; j < 32; j += 4) {
      c0 = fmaf(w[j],   bp(adr[j],   h1T), c0);  // h1n(T-1) broadcast
      c1 = fmaf(w[j+1], bp(adr[j+1], h1T), c1);
      c2 = fmaf(w[j+2], bp(adr[j+2], h1T), c2);
      c3 = fmaf(w[j+3], bp(adr[j+3], h1T), c3);
    }
    if (m == 32) outp[T_LEN - 1] = ((c0 + c1) + (c2 + c3)) + bo;
    if (!up) hf[2048 + b * 32 + r] = h1T;     // h_final layer 1 = h1n(T-1)
  }
}

extern "C" void kernel_launch(void* const* d_in, const int* in_sizes, int n_in,
                              void* d_out, int out_size, void* d_ws, size_t ws_size,
                              hipStream_t stream) {
  rnn2_kernel<<<dim3(B_SZ), dim3(128), 0, stream>>>(
      (const float*)d_in[0],  (const float*)d_in[1],  (const float*)d_in[2],
      (const float*)d_in[3],  (const float*)d_in[4],  (const float*)d_in[5],
      (const float*)d_in[6],  (const float*)d_in[7],  (const float*)d_in[8],
      (const float*)d_in[9],  (const float*)d_in[10], (const float*)d_in[11],
      (float*)d_out);
}